// Round 1
// 1860.653 us; speedup vs baseline: 1.1535x; 1.1535x over previous
//
#include <hip/hip_runtime.h>
#include <hip/hip_bf16.h>
#include <math.h>

typedef __bf16 bf16;
typedef __bf16 bf16x4 __attribute__((ext_vector_type(4)));
typedef __bf16 bf16x8 __attribute__((ext_vector_type(8)));
typedef float f32x4 __attribute__((ext_vector_type(4)));

#define BB 64
#define NN 49
#define CENC 2048
#define SS 26
#define NSTEP 25
#define VV 10000
#define EE 512
#define HH 512
#define AAT 512
#define ALPHA_OFF (BB*NSTEP*VV)

// T16 swizzled layout for MFMA operands: matrix M[R x K] (R%16==0, K%32==0)
// element (r,k) at sw[((rt*KC + kc)*64 + lane)*8 + j]
//   rt=r/16, kc=k/32, lane=((k%32)/8)*16 + (r%16), j=k%8, KC=K/32
// A wave's ldb8(sw + tile*512 + lane*8) is 1KB contiguous -> global_load_lds friendly.

struct Wks {
  float att1[BB*NN*AAT];            // fp32 row-major [3136][512]
  float h[2][BB*HH];                // fp32 state
  float c[2][BB*HH];
  bf16 h_hi[2][BB*HH];              // T16 (R=64,K=512,KC=16)
  bf16 h_lo[2][BB*HH];
  float alpha[BB*64];               // per-step alpha (padded to 64)
  float hwhh[BB*4*HH];              // h @ Whh^T  [64][2048] fp32
  float embg[NSTEP*BB*4*HH];        // xemb @ Wih_e^T + bih + bhh  [1600][2048]
  union {                           // featgates dead after loop; swizzled Wfcn written after loop
    float fg[BB*NN*4*HH];           // feat @ Wih_c^T  [3136][2048] fp32
    struct {
      bf16 Wfcn_hi[10048*HH];       // T16 (R=10000 pad 10048,K=512)
      bf16 Winh_hi[HH*CENC];        // T16 (R=512,K=2048) — dead after k_init
      bf16 Winc_hi[HH*CENC];
    } w;
  } u;
  bf16 mean_hi[BB*CENC];            // T16 (R=64,K=2048)
  bf16 mean_lo[BB*CENC];
  bf16 xemb_hi[NSTEP*BB*EE];        // T16 (R=1600,K=512), row=s*64+b
  bf16 xemb_lo[NSTEP*BB*EE];
  bf16 hist_hi[NSTEP*BB*HH];        // T16 (R=1600,K=512), row=s*64+b
  bf16 hist_lo[NSTEP*BB*HH];
  bf16 Wih_hi[4*HH*(EE+CENC)];      // T16 (R=2048,K=2560,KC=80)
  bf16 Wih_lo[4*HH*(EE+CENC)];
  bf16 Whh_hi[4*HH*HH];             // T16 (R=2048,K=512,KC=16)
  bf16 Whh_lo[4*HH*HH];
  bf16 Wenc_hi[AAT*CENC];           // T16 (R=512,K=2048,KC=64)
  bf16 Wdec_hi[AAT*HH];             // ROW-MAJOR (per-wave row dots)
};

__device__ inline bf16x8 ldb8(const bf16* p){ return *(const bf16x8*)p; }
__device__ inline f32x4 mfma16(bf16x8 a, bf16x8 b, f32x4 c){
  return __builtin_amdgcn_mfma_f32_16x16x32_bf16(a, b, c, 0, 0, 0);
}
__device__ inline float sigm(float x){ return 1.0f/(1.0f+expf(-x)); }

__device__ inline void split8(const float* p, bf16x8& hi, bf16x8& lo){
  float4 v0 = *(const float4*)p;
  float4 v1 = *(const float4*)(p+4);
  float v[8] = {v0.x,v0.y,v0.z,v0.w,v1.x,v1.y,v1.z,v1.w};
  #pragma unroll
  for (int j=0;j<8;j++){ bf16 h=(bf16)v[j]; hi[j]=h; lo[j]=(bf16)(v[j]-(float)h); }
}

// direct-to-LDS 16B per lane (global src per-lane, LDS dst wave-uniform base + lane*16)
__device__ inline void gll16(const bf16* g, bf16* l){
  __builtin_amdgcn_global_load_lds(
      (const __attribute__((address_space(1))) void*)g,
      (__attribute__((address_space(3))) void*)l, 16, 0, 0);
}

// ---------------- plain fp32 -> bf16 hi convert (row-major, Wdec only) -------------
__global__ __launch_bounds__(256) void k_cvt(const float* __restrict__ src,
    bf16* __restrict__ hi, int n4){
  int i = blockIdx.x*256 + threadIdx.x;
  if (i >= n4) return;
  float4 v = ((const float4*)src)[i];
  float a[4] = {v.x, v.y, v.z, v.w};
  bf16x4 hv;
  #pragma unroll
  for (int j=0;j<4;j++) hv[j] = (bf16)a[j];
  *(bf16x4*)(hi + i*4) = hv;
}

// ---------------- fp32 row-major -> T16 swizzle (hi + optional lo) -----------------
__global__ __launch_bounds__(256) void k_cvt_sw(const float* __restrict__ src,
    bf16* __restrict__ hi, bf16* __restrict__ lo, int R, int K, int ntile){
  int g = blockIdx.x*256 + threadIdx.x;
  if (g >= ntile*64) return;
  int tile = g>>6, lane = g&63;
  int KC = K>>5;
  int rt = tile/KC, kc = tile - rt*KC;
  int r = rt*16 + (lane&15);
  if (r >= R) r = R-1;
  int k = kc*32 + (lane>>4)*8;
  bf16x8 hv, lv;
  split8(src + (size_t)r*K + k, hv, lv);
  *(bf16x8*)(hi + (size_t)g*8) = hv;
  if (lo) *(bf16x8*)(lo + (size_t)g*8) = lv;
}

// ---------------- gather caption embeddings -> T16 hi/lo ---------------------------
__global__ __launch_bounds__(256) void k_emb(const int* __restrict__ caps,
    const float* __restrict__ emb, Wks* __restrict__ ws){
  int g = blockIdx.x*256 + threadIdx.x;
  if (g >= 1600*64) return;
  int tile = g>>6, lane = g&63;
  int rt = tile>>4, kc = tile&15;
  int r = rt*16 + (lane&15);
  int s = r>>6, b = r&63;
  int k = kc*32 + (lane>>4)*8;
  int cap = caps[b*SS + s];
  bf16x8 hv, lv;
  split8(emb + (size_t)cap*EE + k, hv, lv);
  *(bf16x8*)(ws->xemb_hi + (size_t)g*8) = hv;
  *(bf16x8*)(ws->xemb_lo + (size_t)g*8) = lv;
}

// ---------------- mean over N=49 pixels -> T16 hi/lo -------------------------------
__global__ __launch_bounds__(256) void k_mean(const float* __restrict__ feat, Wks* __restrict__ ws){
  int idx = blockIdx.x*256 + threadIdx.x;
  int b = idx >> 11, ch = idx & 2047;
  const float* p = feat + (size_t)b*NN*CENC + ch;
  float s = 0.f;
  #pragma unroll
  for (int n=0;n<NN;n++) s += p[n*CENC];
  s *= (1.0f/49.0f);
  bf16 hi = (bf16)s;
  int off = (((b>>4)*64 + (ch>>5))*64 + ((ch&31)>>3)*16 + (b&15))*8 + (ch&7);
  ws->mean_hi[off] = hi;
  ws->mean_lo[off] = (bf16)(s - (float)hi);
}

// ---------------- h0/c0 init (T16 operands) ----------------------------------------
__global__ __launch_bounds__(256) void k_init(Wks* __restrict__ ws,
    const float* __restrict__ bh, const float* __restrict__ bc){
  int wid = threadIdx.x >> 6, lane = threadIdx.x & 63;
  int w = blockIdx.x*4 + wid;                // 0..63
  int mat = w >> 5, nt = w & 31;
  int lane15 = lane & 15, quad = lane >> 4;
  const bf16* Wm = mat ? ws->u.w.Winc_hi : ws->u.w.Winh_hi;
  const float* bm = mat ? bc : bh;
  int col = nt*16 + lane15;
  f32x4 acc[4] = {};
  for (int kc=0; kc<64; kc++){
    bf16x8 bfr = ldb8(Wm + (((size_t)nt*64 + kc)*64 + lane)*8);
    #pragma unroll
    for (int t=0;t<4;t++){
      acc[t] = mfma16(ldb8(ws->mean_hi + (((size_t)t*64 + kc)*64 + lane)*8), bfr, acc[t]);
      acc[t] = mfma16(ldb8(ws->mean_lo + (((size_t)t*64 + kc)*64 + lane)*8), bfr, acc[t]);
    }
  }
  float bias = bm[col];
  #pragma unroll
  for (int t=0;t<4;t++){
    #pragma unroll
    for (int r=0;r<4;r++){
      int b = t*16 + quad*4 + r;
      float v = acc[t][r] + bias;
      if (mat == 0){
        ws->h[0][b*HH + col] = v;
        bf16 hi = (bf16)v;
        int off = (((b>>4)*16 + (col>>5))*64 + ((col&31)>>3)*16 + (b&15))*8 + (col&7);
        ws->h_hi[0][off] = hi;
        ws->h_lo[0][off] = (bf16)(v - (float)hi);
      } else {
        ws->c[0][b*HH + col] = v;
      }
    }
  }
}

// ---------------- embgates = xemb @ Wih_e^T + bih + bhh  [1600][2048] --------------
__global__ __launch_bounds__(256) void k_embg(Wks* __restrict__ ws,
    const float* __restrict__ bih, const float* __restrict__ bhh){
  int wid = threadIdx.x>>6, lane = threadIdx.x&63;
  int w = blockIdx.x*4 + wid;                // 3200 waves: w = nt*25 + mtg
  int nt = w/25, mtg = w - nt*25;            // nt<128 (j-tiles), mtg<25 (4 row-tiles each)
  int lane15 = lane&15, quad = lane>>4;
  f32x4 acc[4] = {};
  for (int kc=0; kc<16; kc++){
    bf16x8 wh = ldb8(ws->Wih_hi + (((size_t)nt*80 + kc)*64 + lane)*8);
    bf16x8 wl = ldb8(ws->Wih_lo + (((size_t)nt*80 + kc)*64 + lane)*8);
    #pragma unroll
    for (int i=0;i<4;i++){
      int rt = mtg*4 + i;
      bf16x8 ah = ldb8(ws->xemb_hi + (((size_t)rt*16 + kc)*64 + lane)*8);
      bf16x8 al = ldb8(ws->xemb_lo + (((size_t)rt*16 + kc)*64 + lane)*8);
      acc[i] = mfma16(ah, wh, acc[i]);
      acc[i] = mfma16(al, wh, acc[i]);
      acc[i] = mfma16(ah, wl, acc[i]);
    }
  }
  int col = nt*16 + lane15;
  float bias = bih[col] + bhh[col];
  #pragma unroll
  for (int i=0;i<4;i++){
    #pragma unroll
    for (int r=0;r<4;r++){
      int row = (mtg*4+i)*16 + quad*4 + r;   // row = s*64 + b
      ws->embg[(size_t)row*(4*HH) + col] = acc[i][r] + bias;
    }
  }
}

// ---------------- encoder GEMM: att1 + featgates in one pass over feat -------------
// C[3136, 2560] = feat[3136,2048] @ [Wih_c ; Wenc]^T, LDS-staged, double-buffered.
// grid: 49 m-blocks (BM=64) x 20 n-groups (BN=128): nb<16 -> featgates, nb>=16 -> att1.
__global__ __launch_bounds__(256) void k_enc(const float* __restrict__ feat,
    const float* __restrict__ benc, Wks* __restrict__ ws)
{
  __shared__ bf16 sm[2][24*512];             // [buf][tile 0..7 = A hi/lo, 8..23 = B][512]
  int bid = blockIdx.x;
  int mb = bid % 49, nb = bid / 49;
  int tid = threadIdx.x, wid = tid>>6, lane = tid&63;
  int lane15 = lane&15, quad = lane>>4;
  bool is_fg = (nb < 16);
  // A-staging map: thread -> (row rr, k-octet qo) of the 64x32 fp32 tile
  int rr = tid>>2, qo = tid&3;
  const float* arow = feat + (size_t)(mb*64 + rr)*CENC + qo*8;
  int a_ds = ((rr>>4)*2)*512 + (qo*16 + (rr&15))*8;   // hi tile rt*2, lo at +512

  f32x4 acc[8] = {};

  auto stageB = [&](int kc, int buf){
    if (is_fg){
      #pragma unroll
      for (int j=0;j<4;j++){
        int tt = wid*4 + j;                  // 16 tiles: nt_loc = tt>>1, hi/lo = tt&1
        int ntl = tt>>1;
        const bf16* src = ((tt&1) ? ws->Wih_lo : ws->Wih_hi)
            + (size_t)((nb*8 + ntl)*80 + 16 + kc)*512 + lane*8;
        gll16(src, &sm[buf][(8+tt)*512]);
      }
    } else {
      #pragma unroll
      for (int j=0;j<2;j++){
        int tt = wid*2 + j;                  // 8 tiles, hi only
        const bf16* src = ws->Wenc_hi
            + (size_t)(((nb-16)*8 + tt)*64 + kc)*512 + lane*8;
        gll16(src, &sm[buf][(8+tt)*512]);
      }
    }
  };
  auto cvtwr = [&](int buf, float4 v0, float4 v1){
    float v[8] = {v0.x,v0.y,v0.z,v0.w,v1.x,v1.y,v1.z,v1.w};
    bf16x8 hv, lv;
    #pragma unroll
    for (int j=0;j<8;j++){ bf16 h=(bf16)v[j]; hv[j]=h; lv[j]=(bf16)(v[j]-(float)h); }
    *(bf16x8*)(&sm[buf][a_ds]) = hv;
    *(bf16x8*)(&sm[buf][a_ds+512]) = lv;
  };

  // prologue: stage kc=0 into buf 0
  stageB(0, 0);
  { float4 v0 = *(const float4*)arow;
    float4 v1 = *(const float4*)(arow+4);
    cvtwr(0, v0, v1); }
  __syncthreads();

  for (int kc=0; kc<64; kc++){
    int cur = kc & 1;
    bool pf = (kc < 63);
    float4 v0, v1;
    if (pf){
      stageB(kc+1, cur^1);
      const float* p = arow + (kc+1)*32;
      v0 = *(const float4*)p; v1 = *(const float4*)(p+4);
    }
    const bf16* S = sm[cur];
    bf16x8 ah = ldb8(S + (wid*2)*512 + lane*8);
    bf16x8 al = ldb8(S + (wid*2+1)*512 + lane*8);
    if (is_fg){
      #pragma unroll
      for (int u=0;u<8;u++){
        bf16x8 wh = ldb8(S + (size_t)(8+u*2)*512 + lane*8);
        bf16x8 wl = ldb8(S + (size_t)(9+u*2)*512 + lane*8);
        acc[u] = mfma16(ah, wh, acc[u]);
        acc[u] = mfma16(al, wh, acc[u]);
        acc[u] = mfma16(ah, wl, acc[u]);
      }
    } else {
      #pragma unroll
      for (int u=0;u<8;u++){
        bf16x8 wh = ldb8(S + (size_t)(8+u)*512 + lane*8);
        acc[u] = mfma16(ah, wh, acc[u]);
        acc[u] = mfma16(al, wh, acc[u]);
      }
    }
    if (pf) cvtwr(cur^1, v0, v1);
    __syncthreads();
  }

  if (is_fg){
    #pragma unroll
    for (int u=0;u<8;u++){
      int col = nb*128 + u*16 + lane15;
      #pragma unroll
      for (int r=0;r<4;r++){
        int row = mb*64 + wid*16 + quad*4 + r;
        ws->u.fg[(size_t)row*(4*HH) + col] = acc[u][r];
      }
    }
  } else {
    #pragma unroll
    for (int u=0;u<8;u++){
      int col = (nb-16)*128 + u*16 + lane15;
      float bias = benc[col];
      #pragma unroll
      for (int r=0;r<4;r++){
        int row = mb*64 + wid*16 + quad*4 + r;
        ws->att1[(size_t)row*AAT + col] = acc[u][r] + bias;
      }
    }
  }
}

// ---------------- per-step A: attention (blocks 0..63) + hWhh (blocks 64..191) -----
__global__ __launch_bounds__(256) void k_sa(
    int t, int par, const float* __restrict__ bdec,
    const float* __restrict__ Wfull, const float* __restrict__ bfull,
    Wks* __restrict__ ws, float* __restrict__ out)
{
  int tid = threadIdx.x;
  int wid = tid>>6, lane = tid&63;
  if (blockIdx.x >= 64){
    // hwhh[b][j] = (h @ Whh^T)[b][j], fp32, T16 MFMA
    int w = (blockIdx.x - 64)*4 + wid;       // 0..511
    int nt = w>>2, mq = w&3;                 // j-tile, b-tile
    int lane15 = lane&15, quad = lane>>4;
    f32x4 acc = {};
    #pragma unroll 4
    for (int kc=0;kc<16;kc++){
      bf16x8 ah = ldb8(ws->h_hi[par] + ((size_t)(mq*16+kc)*64 + lane)*8);
      bf16x8 al = ldb8(ws->h_lo[par] + ((size_t)(mq*16+kc)*64 + lane)*8);
      bf16x8 wh = ldb8(ws->Whh_hi + ((size_t)(nt*16+kc)*64 + lane)*8);
      bf16x8 wl = ldb8(ws->Whh_lo + ((size_t)(nt*16+kc)*64 + lane)*8);
      acc = mfma16(ah, wh, acc);
      acc = mfma16(al, wh, acc);
      acc = mfma16(ah, wl, acc);
    }
    int col = nt*16 + lane15;
    #pragma unroll
    for (int r=0;r<4;r++){
      int b = mq*16 + quad*4 + r;
      ws->hwhh[b*(4*HH) + col] = acc[r];
    }
    return;
  }
  int b = blockIdx.x;
  __shared__ float sh_att2[512];
  __shared__ float sh_wf[512];
  __shared__ float sh_e[64];
  sh_wf[tid] = Wfull[tid]; sh_wf[tid+256] = Wfull[tid+256];
  float h8[8];
  {
    const float* hp = ws->h[par] + b*HH + lane*8;
    #pragma unroll
    for (int j=0;j<8;j++) h8[j] = hp[j];
  }
  // att2: per-wave row dots over row-major bf16 Wdec
  {
    const bf16* wd = ws->Wdec_hi + (size_t)wid*128*HH + lane*8;
    #pragma unroll 2
    for (int r=0;r<128;r+=2){
      bf16x8 w0 = ldb8(wd + (size_t)r*HH);
      bf16x8 w1 = ldb8(wd + (size_t)(r+1)*HH);
      float s0=0.f, s1=0.f;
      #pragma unroll
      for (int j=0;j<8;j++){ s0 += (float)w0[j]*h8[j]; s1 += (float)w1[j]*h8[j]; }
      #pragma unroll
      for (int off=32; off; off>>=1){ s0 += __shfl_xor(s0,off,64); s1 += __shfl_xor(s1,off,64); }
      if (lane==0){
        int a0 = wid*128 + r;
        sh_att2[a0]   = s0 + bdec[a0];
        sh_att2[a0+1] = s1 + bdec[a0+1];
      }
    }
  }
  __syncthreads();
  for (int n = wid; n < NN; n += 4){
    const float* at1 = ws->att1 + (size_t)(b*NN + n)*AAT + lane*8;
    const float* a2p = sh_att2 + lane*8;
    const float* wfp = sh_wf + lane*8;
    float s = 0.f;
    #pragma unroll
    for (int j=0;j<8;j++){
      float v = at1[j] + a2p[j];
      v = fmaxf(v, 0.0f);
      s += v * wfp[j];
    }
    #pragma unroll
    for (int off=32; off; off>>=1) s += __shfl_xor(s, off, 64);
    if (lane==0) sh_e[n] = s + bfull[0];
  }
  __syncthreads();
  if (wid == 0){
    float e = (lane < NN) ? sh_e[lane] : -1e30f;
    float m = e;
    #pragma unroll
    for (int off=32; off; off>>=1) m = fmaxf(m, __shfl_xor(m, off, 64));
    float p = (lane < NN) ? expf(e - m) : 0.0f;
    float sum = p;
    #pragma unroll
    for (int off=32; off; off>>=1) sum += __shfl_xor(sum, off, 64);
    float al = p / sum;
    if (lane < NN){
      ws->alpha[b*64 + lane] = al;
      out[ALPHA_OFF + (size_t)(b*NSTEP + t)*NN + lane] = al;
    }
  }
}

// ---------------- per-step B: gates = embg + sum_n alpha*fg + hwhh; LSTM -----------
__global__ __launch_bounds__(128) void k_sb(int s, int par, Wks* __restrict__ ws)
{
  int bid = blockIdx.x;
  int b = bid>>2, jq = bid&3;
  int tid = threadIdx.x;
  int jj = jq*128 + tid;                     // [0,512)
  __shared__ float sal[64];
  if (tid < 64) sal[tid] = (tid < NN) ? ws->alpha[b*64 + tid] : 0.f;
  __syncthreads();
  size_t eoff = ((size_t)(s*64 + b))*(4*HH) + jj;
  size_t hoff = (size_t)b*(4*HH) + jj;
  float gi = ws->embg[eoff]           + ws->hwhh[hoff];
  float gf = ws->embg[eoff + 512]     + ws->hwhh[hoff + 512];
  float gg = ws->embg[eoff + 1024]    + ws->hwhh[hoff + 1024];
  float go = ws->embg[eoff + 1536]    + ws->hwhh[hoff + 1536];
  const float* fgp = ws->u.fg + (size_t)b*NN*(4*HH) + jj;
  #pragma unroll 7
  for (int n=0;n<NN;n++){
    float a = sal[n];
    gi += a*fgp[0];
    gf += a*fgp[512];
    gg += a*fgp[1024];
    go += a*fgp[1536];
    fgp += 4*HH;
  }
  float co = ws->c[par][b*HH + jj];
  float cn = sigm(gf)*co + sigm(gi)*tanhf(gg);
  float hn = sigm(go)*tanhf(cn);
  int p2 = par ^ 1;
  ws->c[p2][b*HH + jj] = cn;
  ws->h[p2][b*HH + jj] = hn;
  bf16 hi = (bf16)hn;
  bf16 lo = (bf16)(hn - (float)hi);
  int kc = jj>>5, lane_w = ((jj&31)>>3)*16 + (b&15), j8 = jj&7;
  int offh = (((b>>4)*16 + kc)*64 + lane_w)*8 + j8;
  ws->h_hi[p2][offh] = hi;
  ws->h_lo[p2][offh] = lo;
  size_t offhist = ((((size_t)s*4 + (b>>4))*16 + kc)*64 + lane_w)*8 + j8;
  ws->hist_hi[offhist] = hi;
  ws->hist_lo[offhist] = lo;
}

// ---------------- final pred GEMM: [1600 x 10000] = hist @ Wfcn^T (T16) ------------
__global__ __launch_bounds__(256) void k_pred(Wks* __restrict__ ws,
    const float* __restrict__ bfcn, float* __restrict__ out)
{
  int wid = threadIdx.x>>6, lane = threadIdx.x&63;
  int mt = blockIdx.y*4 + wid;
  int nt = blockIdx.x;
  if (mt >= NSTEP) return;
  int lane15 = lane&15, quad = lane>>4;
  int n0 = nt*64;
  f32x4 acc[4][4] = {};
  for (int kc=0; kc<16; kc++){
    bf16x8 a_hi[4], a_lo[4], bw[4];
    #pragma unroll
    for (int i=0;i<4;i++){
      a_hi[i] = ldb8(ws->hist_hi + (((size_t)(mt*4+i)*16 + kc)*64 + lane)*8);
      a_lo[i] = ldb8(ws->hist_lo + (((size_t)(mt*4+i)*16 + kc)*64 + lane)*8);
    }
    #pragma unroll
    for (int u=0;u<4;u++)
      bw[u] = ldb8(ws->u.w.Wfcn_hi + (((size_t)(nt*4+u)*16 + kc)*64 + lane)*8);
    #pragma unroll
    for (int u=0;u<4;u++){
      #pragma unroll
      for (int i=0;i<4;i++){
        acc[u][i] = mfma16(a_hi[i], bw[u], acc[u][i]);
        acc[u][i] = mfma16(a_lo[i], bw[u], acc[u][i]);
      }
    }
  }
  #pragma unroll
  for (int u=0;u<4;u++){
    int vc = n0 + u*16 + lane15;
    if (vc < VV){
      float bias = bfcn[vc];
      #pragma unroll
      for (int i=0;i<4;i++){
        #pragma unroll
        for (int r=0;r<4;r++){
          int row = mt*64 + i*16 + quad*4 + r;   // row = s*64 + b
          int sstep = row >> 6, bidx = row & 63;
          out[(size_t)(bidx*NSTEP + sstep)*VV + vc] = acc[u][i][r] + bias;
        }
      }
    }
  }
}

extern "C" void kernel_launch(void* const* d_in, const int* in_sizes, int n_in,
                              void* d_out, int out_size, void* d_ws, size_t ws_size,
                              hipStream_t stream)
{
  const float* feat = (const float*)d_in[0];
  const int*   caps = (const int*)d_in[1];
  const float* emb  = (const float*)d_in[2];
  const float* Wih  = (const float*)d_in[3];
  const float* bih  = (const float*)d_in[4];
  const float* Whh  = (const float*)d_in[5];
  const float* bhh  = (const float*)d_in[6];
  const float* Wenc = (const float*)d_in[7];
  const float* benc = (const float*)d_in[8];
  const float* Wdec = (const float*)d_in[9];
  const float* bdec = (const float*)d_in[10];
  const float* Wfull= (const float*)d_in[11];
  const float* bfull= (const float*)d_in[12];
  const float* Winh = (const float*)d_in[13];
  const float* binh = (const float*)d_in[14];
  const float* Winc = (const float*)d_in[15];
  const float* binc = (const float*)d_in[16];
  const float* Wfcn = (const float*)d_in[17];
  const float* bfcn = (const float*)d_in[18];
  float* out = (float*)d_out;
  Wks* ws = (Wks*)d_ws;
  if (ws_size < sizeof(Wks)) return;

  #define SW(src, hi, lo, R, K) do { int nt_ = ((R+15)/16)*((K)/32); \
    hipLaunchKernelGGL(k_cvt_sw, dim3((nt_*64+255)/256), dim3(256), 0, stream, \
        src, hi, lo, R, K, nt_); } while(0)
  SW(Wih,  ws->Wih_hi,  ws->Wih_lo,  2048, 2560);
  SW(Whh,  ws->Whh_hi,  ws->Whh_lo,  2048, 512);
  SW(Wenc, ws->Wenc_hi, (bf16*)nullptr, 512, 2048);
  SW(Winh, ws->u.w.Winh_hi, (bf16*)nullptr, 512, 2048);
  SW(Winc, ws->u.w.Winc_hi, (bf16*)nullptr, 512, 2048);
  hipLaunchKernelGGL(k_cvt, dim3((AAT*HH/4+255)/256), dim3(256), 0, stream, Wdec, ws->Wdec_hi, AAT*HH/4);
  hipLaunchKernelGGL(k_emb, dim3(400), dim3(256), 0, stream, caps, emb, ws);
  hipLaunchKernelGGL(k_mean, dim3(512), dim3(256), 0, stream, feat, ws);
  hipLaunchKernelGGL(k_init, dim3(16), dim3(256), 0, stream, ws, binh, binc);
  hipLaunchKernelGGL(k_embg, dim3(800), dim3(256), 0, stream, ws, bih, bhh);
  hipLaunchKernelGGL(k_enc, dim3(980), dim3(256), 0, stream, feat, benc, ws);
  for (int t=0; t<NSTEP; t++){
    hipLaunchKernelGGL(k_sa, dim3(192), dim3(256), 0, stream,
        t, t&1, bdec, Wfull, bfull, ws, out);
    hipLaunchKernelGGL(k_sb, dim3(256), dim3(128), 0, stream, t, t&1, ws);
  }
  // fg dead now: reuse its space for the Wfcn swizzle, then pred
  SW(Wfcn, ws->u.w.Wfcn_hi, (bf16*)nullptr, 10000, 512);
  #undef SW
  hipLaunchKernelGGL(k_pred, dim3(157, 7), dim3(256), 0, stream, ws, bfcn, out);
}

// Round 2
// 1758.039 us; speedup vs baseline: 1.2208x; 1.0584x over previous
//
#include <hip/hip_runtime.h>
#include <hip/hip_cooperative_groups.h>
#include <hip/hip_bf16.h>
#include <math.h>

namespace cg = cooperative_groups;

typedef __bf16 bf16;
typedef __bf16 bf16x4 __attribute__((ext_vector_type(4)));
typedef __bf16 bf16x8 __attribute__((ext_vector_type(8)));
typedef float f32x4 __attribute__((ext_vector_type(4)));

#define BB 64
#define NN 49
#define CENC 2048
#define SS 26
#define NSTEP 25
#define VV 10000
#define EE 512
#define HH 512
#define AAT 512
#define ALPHA_OFF (BB*NSTEP*VV)

// T16 swizzled layout for MFMA operands: matrix M[R x K] (R%16==0, K%32==0)
// element (r,k) at sw[((rt*KC + kc)*64 + lane)*8 + j]
//   rt=r/16, kc=k/32, lane=((k%32)/8)*16 + (r%16), j=k%8, KC=K/32

struct Wks {
  float att1[BB*NN*AAT];            // fp32 row-major [3136][512]
  float h[2][BB*HH];                // fp32 state (init only)
  float c[2][BB*HH];
  bf16 h_hi[2][BB*HH];              // T16 (R=64,K=512,KC=16)
  bf16 h_lo[2][BB*HH];
  float att2[BB*AAT];               // per-step h @ Wdec^T + bdec
  float hwhh[BB*4*HH];              // h @ Whh^T  [64][2048] fp32
  float embg[NSTEP*BB*4*HH];        // xemb @ Wih_e^T + bih + bhh  [1600][2048]
  union {                           // featgates dead after loop
    float fg[BB*NN*4*HH];           // feat @ Wih_c^T  [3136][2048] fp32
    struct {
      bf16 Wfcn_hi[10048*HH];       // T16 (R=10000 pad 10048,K=512)
      bf16 Winh_hi[HH*CENC];        // T16 (R=512,K=2048) — dead after k_init
      bf16 Winc_hi[HH*CENC];
    } w;
  } u;
  bf16 mean_hi[BB*CENC];            // T16 (R=64,K=2048)
  bf16 mean_lo[BB*CENC];
  bf16 xemb_hi[NSTEP*BB*EE];        // T16 (R=1600,K=512), row=s*64+b
  bf16 xemb_lo[NSTEP*BB*EE];
  bf16 hist_hi[NSTEP*BB*HH];        // T16 (R=1600,K=512), row=s*64+b
  bf16 hist_lo[NSTEP*BB*HH];
  bf16 Wih_hi[4*HH*(EE+CENC)];      // T16 (R=2048,K=2560,KC=80)
  bf16 Wih_lo[4*HH*(EE+CENC)];
  bf16 Whh_hi[4*HH*HH];             // T16 (R=2048,K=512,KC=16)
  bf16 Whh_lo[4*HH*HH];
  bf16 Wenc_hi[AAT*CENC];           // T16 (R=512,K=2048,KC=64)
  bf16 Wdec_hi[AAT*HH];             // T16 (R=512,K=512,KC=16)
};

__device__ inline bf16x8 ldb8(const bf16* p){ return *(const bf16x8*)p; }
__device__ inline f32x4 mfma16(bf16x8 a, bf16x8 b, f32x4 c){
  return __builtin_amdgcn_mfma_f32_16x16x32_bf16(a, b, c, 0, 0, 0);
}
__device__ inline float sigm(float x){ return 1.0f/(1.0f+expf(-x)); }

__device__ inline void split8(const float* p, bf16x8& hi, bf16x8& lo){
  float4 v0 = *(const float4*)p;
  float4 v1 = *(const float4*)(p+4);
  float v[8] = {v0.x,v0.y,v0.z,v0.w,v1.x,v1.y,v1.z,v1.w};
  #pragma unroll
  for (int j=0;j<8;j++){ bf16 h=(bf16)v[j]; hi[j]=h; lo[j]=(bf16)(v[j]-(float)h); }
}

// direct-to-LDS 16B per lane (global src per-lane, LDS dst wave-uniform base + lane*16)
__device__ inline void gll16(const bf16* g, bf16* l){
  __builtin_amdgcn_global_load_lds(
      (const __attribute__((address_space(1))) void*)g,
      (__attribute__((address_space(3))) void*)l, 16, 0, 0);
}

// ---------------- fp32 row-major -> T16 swizzle (hi + optional lo) -----------------
__global__ __launch_bounds__(256) void k_cvt_sw(const float* __restrict__ src,
    bf16* __restrict__ hi, bf16* __restrict__ lo, int R, int K, int ntile){
  int g = blockIdx.x*256 + threadIdx.x;
  if (g >= ntile*64) return;
  int tile = g>>6, lane = g&63;
  int KC = K>>5;
  int rt = tile/KC, kc = tile - rt*KC;
  int r = rt*16 + (lane&15);
  if (r >= R) r = R-1;
  int k = kc*32 + (lane>>4)*8;
  bf16x8 hv, lv;
  split8(src + (size_t)r*K + k, hv, lv);
  *(bf16x8*)(hi + (size_t)g*8) = hv;
  if (lo) *(bf16x8*)(lo + (size_t)g*8) = lv;
}

// ---------------- gather caption embeddings -> T16 hi/lo ---------------------------
__global__ __launch_bounds__(256) void k_emb(const int* __restrict__ caps,
    const float* __restrict__ emb, Wks* __restrict__ ws){
  int g = blockIdx.x*256 + threadIdx.x;
  if (g >= 1600*64) return;
  int tile = g>>6, lane = g&63;
  int rt = tile>>4, kc = tile&15;
  int r = rt*16 + (lane&15);
  int s = r>>6, b = r&63;
  int k = kc*32 + (lane>>4)*8;
  int cap = caps[b*SS + s];
  bf16x8 hv, lv;
  split8(emb + (size_t)cap*EE + k, hv, lv);
  *(bf16x8*)(ws->xemb_hi + (size_t)g*8) = hv;
  *(bf16x8*)(ws->xemb_lo + (size_t)g*8) = lv;
}

// ---------------- mean over N=49 pixels -> T16 hi/lo -------------------------------
__global__ __launch_bounds__(256) void k_mean(const float* __restrict__ feat, Wks* __restrict__ ws){
  int idx = blockIdx.x*256 + threadIdx.x;
  int b = idx >> 11, ch = idx & 2047;
  const float* p = feat + (size_t)b*NN*CENC + ch;
  float s = 0.f;
  #pragma unroll
  for (int n=0;n<NN;n++) s += p[n*CENC];
  s *= (1.0f/49.0f);
  bf16 hi = (bf16)s;
  int off = (((b>>4)*64 + (ch>>5))*64 + ((ch&31)>>3)*16 + (b&15))*8 + (ch&7);
  ws->mean_hi[off] = hi;
  ws->mean_lo[off] = (bf16)(s - (float)hi);
}

// ---------------- h0/c0 init (T16 operands) ----------------------------------------
__global__ __launch_bounds__(256) void k_init(Wks* __restrict__ ws,
    const float* __restrict__ bh, const float* __restrict__ bc){
  int wid = threadIdx.x >> 6, lane = threadIdx.x & 63;
  int w = blockIdx.x*4 + wid;                // 0..63
  int mat = w >> 5, nt = w & 31;
  int lane15 = lane & 15, quad = lane >> 4;
  const bf16* Wm = mat ? ws->u.w.Winc_hi : ws->u.w.Winh_hi;
  const float* bm = mat ? bc : bh;
  int col = nt*16 + lane15;
  f32x4 acc[4] = {};
  for (int kc=0; kc<64; kc++){
    bf16x8 bfr = ldb8(Wm + (((size_t)nt*64 + kc)*64 + lane)*8);
    #pragma unroll
    for (int t=0;t<4;t++){
      acc[t] = mfma16(ldb8(ws->mean_hi + (((size_t)t*64 + kc)*64 + lane)*8), bfr, acc[t]);
      acc[t] = mfma16(ldb8(ws->mean_lo + (((size_t)t*64 + kc)*64 + lane)*8), bfr, acc[t]);
    }
  }
  float bias = bm[col];
  #pragma unroll
  for (int t=0;t<4;t++){
    #pragma unroll
    for (int r=0;r<4;r++){
      int b = t*16 + quad*4 + r;
      float v = acc[t][r] + bias;
      if (mat == 0){
        ws->h[0][b*HH + col] = v;
        bf16 hi = (bf16)v;
        int off = (((b>>4)*16 + (col>>5))*64 + ((col&31)>>3)*16 + (b&15))*8 + (col&7);
        ws->h_hi[0][off] = hi;
        ws->h_lo[0][off] = (bf16)(v - (float)hi);
      } else {
        ws->c[0][b*HH + col] = v;
      }
    }
  }
}

// ---------------- embgates = xemb @ Wih_e^T + bih + bhh  [1600][2048] --------------
__global__ __launch_bounds__(256) void k_embg(Wks* __restrict__ ws,
    const float* __restrict__ bih, const float* __restrict__ bhh){
  int wid = threadIdx.x>>6, lane = threadIdx.x&63;
  int w = blockIdx.x*4 + wid;                // 3200 waves: w = nt*25 + mtg
  int nt = w/25, mtg = w - nt*25;
  int lane15 = lane&15, quad = lane>>4;
  f32x4 acc[4] = {};
  for (int kc=0; kc<16; kc++){
    bf16x8 wh = ldb8(ws->Wih_hi + (((size_t)nt*80 + kc)*64 + lane)*8);
    bf16x8 wl = ldb8(ws->Wih_lo + (((size_t)nt*80 + kc)*64 + lane)*8);
    #pragma unroll
    for (int i=0;i<4;i++){
      int rt = mtg*4 + i;
      bf16x8 ah = ldb8(ws->xemb_hi + (((size_t)rt*16 + kc)*64 + lane)*8);
      bf16x8 al = ldb8(ws->xemb_lo + (((size_t)rt*16 + kc)*64 + lane)*8);
      acc[i] = mfma16(ah, wh, acc[i]);
      acc[i] = mfma16(al, wh, acc[i]);
      acc[i] = mfma16(ah, wl, acc[i]);
    }
  }
  int col = nt*16 + lane15;
  float bias = bih[col] + bhh[col];
  #pragma unroll
  for (int i=0;i<4;i++){
    #pragma unroll
    for (int r=0;r<4;r++){
      int row = (mtg*4+i)*16 + quad*4 + r;   // row = s*64 + b
      ws->embg[(size_t)row*(4*HH) + col] = acc[i][r] + bias;
    }
  }
}

// ---------------- encoder GEMM: att1 + featgates in one pass over feat -------------
__global__ __launch_bounds__(256) void k_enc(const float* __restrict__ feat,
    const float* __restrict__ benc, Wks* __restrict__ ws)
{
  __shared__ bf16 sm[2][24*512];
  int bid = blockIdx.x;
  int mb = bid % 49, nb = bid / 49;
  int tid = threadIdx.x, wid = tid>>6, lane = tid&63;
  int lane15 = lane&15, quad = lane>>4;
  bool is_fg = (nb < 16);
  int rr = tid>>2, qo = tid&3;
  const float* arow = feat + (size_t)(mb*64 + rr)*CENC + qo*8;
  int a_ds = ((rr>>4)*2)*512 + (qo*16 + (rr&15))*8;

  f32x4 acc[8] = {};

  auto stageB = [&](int kc, int buf){
    if (is_fg){
      #pragma unroll
      for (int j=0;j<4;j++){
        int tt = wid*4 + j;
        int ntl = tt>>1;
        const bf16* src = ((tt&1) ? ws->Wih_lo : ws->Wih_hi)
            + (size_t)((nb*8 + ntl)*80 + 16 + kc)*512 + lane*8;
        gll16(src, &sm[buf][(8+tt)*512]);
      }
    } else {
      #pragma unroll
      for (int j=0;j<2;j++){
        int tt = wid*2 + j;
        const bf16* src = ws->Wenc_hi
            + (size_t)(((nb-16)*8 + tt)*64 + kc)*512 + lane*8;
        gll16(src, &sm[buf][(8+tt)*512]);
      }
    }
  };
  auto cvtwr = [&](int buf, float4 v0, float4 v1){
    float v[8] = {v0.x,v0.y,v0.z,v0.w,v1.x,v1.y,v1.z,v1.w};
    bf16x8 hv, lv;
    #pragma unroll
    for (int j=0;j<8;j++){ bf16 h=(bf16)v[j]; hv[j]=h; lv[j]=(bf16)(v[j]-(float)h); }
    *(bf16x8*)(&sm[buf][a_ds]) = hv;
    *(bf16x8*)(&sm[buf][a_ds+512]) = lv;
  };

  stageB(0, 0);
  { float4 v0 = *(const float4*)arow;
    float4 v1 = *(const float4*)(arow+4);
    cvtwr(0, v0, v1); }
  __syncthreads();

  for (int kc=0; kc<64; kc++){
    int cur = kc & 1;
    bool pf = (kc < 63);
    float4 v0, v1;
    if (pf){
      stageB(kc+1, cur^1);
      const float* p = arow + (kc+1)*32;
      v0 = *(const float4*)p; v1 = *(const float4*)(p+4);
    }
    const bf16* S = sm[cur];
    bf16x8 ah = ldb8(S + (wid*2)*512 + lane*8);
    bf16x8 al = ldb8(S + (wid*2+1)*512 + lane*8);
    if (is_fg){
      #pragma unroll
      for (int u=0;u<8;u++){
        bf16x8 wh = ldb8(S + (size_t)(8+u*2)*512 + lane*8);
        bf16x8 wl = ldb8(S + (size_t)(9+u*2)*512 + lane*8);
        acc[u] = mfma16(ah, wh, acc[u]);
        acc[u] = mfma16(al, wh, acc[u]);
        acc[u] = mfma16(ah, wl, acc[u]);
      }
    } else {
      #pragma unroll
      for (int u=0;u<8;u++){
        bf16x8 wh = ldb8(S + (size_t)(8+u)*512 + lane*8);
        acc[u] = mfma16(ah, wh, acc[u]);
        acc[u] = mfma16(al, wh, acc[u]);
      }
    }
    if (pf) cvtwr(cur^1, v0, v1);
    __syncthreads();
  }

  if (is_fg){
    #pragma unroll
    for (int u=0;u<8;u++){
      int col = nb*128 + u*16 + lane15;
      #pragma unroll
      for (int r=0;r<4;r++){
        int row = mb*64 + wid*16 + quad*4 + r;
        ws->u.fg[(size_t)row*(4*HH) + col] = acc[u][r];
      }
    }
  } else {
    #pragma unroll
    for (int u=0;u<8;u++){
      int col = (nb-16)*128 + u*16 + lane15;
      float bias = benc[col];
      #pragma unroll
      for (int r=0;r<4;r++){
        int row = mb*64 + wid*16 + quad*4 + r;
        ws->att1[(size_t)row*AAT + col] = acc[u][r] + bias;
      }
    }
  }
}

// ---------------- persistent cooperative step loop ---------------------------------
// grid = 128 blocks x 256. Per step:
//   phase A (blocks 0..39, 160 waves): [64 x 2560] = h @ [Whh ; Wdec]^T -> hwhh, att2
//   grid.sync()
//   phase C (all blocks; block = (b, jhalf)): block-local softmax -> alpha,
//     gates = embg + sum_n alpha*fg + hwhh, LSTM pointwise, h/hist writes
//   grid.sync()
__global__ __launch_bounds__(256) void k_loop(Wks* __restrict__ ws,
    const float* __restrict__ bdec, const float* __restrict__ Wfull,
    float* __restrict__ out)
{
  cg::grid_group grid = cg::this_grid();
  int blk = blockIdx.x;
  int tid = threadIdx.x;
  int wid = tid>>6, lane = tid&63;
  int lane15 = lane&15, quad = lane>>4;
  __shared__ float sh_wf[512];
  __shared__ float sh_a2[512];
  __shared__ float sh_e[64];
  __shared__ float sal[64];
  sh_wf[tid] = Wfull[tid];
  sh_wf[tid+256] = Wfull[tid+256];
  int b = blk>>1, jhalf = blk&1;
  int jj = jhalf*256 + tid;                  // [0,512)

  for (int t=0; t<NSTEP; t++){
    int par = t&1, p2 = par^1;
    // ---- phase A ----
    if (blk < 40){
      int ct = blk*4 + wid;                  // 0..159
      f32x4 acc[4] = {};
      if (ct < 128){
        for (int kc=0; kc<16; kc++){
          bf16x8 wh = ldb8(ws->Whh_hi + (((size_t)ct*16 + kc)*64 + lane)*8);
          bf16x8 wl = ldb8(ws->Whh_lo + (((size_t)ct*16 + kc)*64 + lane)*8);
          #pragma unroll
          for (int r=0;r<4;r++){
            bf16x8 ah = ldb8(ws->h_hi[par] + (((size_t)r*16 + kc)*64 + lane)*8);
            bf16x8 al = ldb8(ws->h_lo[par] + (((size_t)r*16 + kc)*64 + lane)*8);
            acc[r] = mfma16(ah, wh, acc[r]);
            acc[r] = mfma16(al, wh, acc[r]);
            acc[r] = mfma16(ah, wl, acc[r]);
          }
        }
        int col = ct*16 + lane15;
        #pragma unroll
        for (int r=0;r<4;r++){
          #pragma unroll
          for (int q=0;q<4;q++){
            int bb = r*16 + quad*4 + q;
            ws->hwhh[bb*(4*HH) + col] = acc[r][q];
          }
        }
      } else {
        int ct2 = ct - 128;                  // 0..31
        for (int kc=0; kc<16; kc++){
          bf16x8 wh = ldb8(ws->Wdec_hi + (((size_t)ct2*16 + kc)*64 + lane)*8);
          #pragma unroll
          for (int r=0;r<4;r++){
            bf16x8 ah = ldb8(ws->h_hi[par] + (((size_t)r*16 + kc)*64 + lane)*8);
            bf16x8 al = ldb8(ws->h_lo[par] + (((size_t)r*16 + kc)*64 + lane)*8);
            acc[r] = mfma16(ah, wh, acc[r]);
            acc[r] = mfma16(al, wh, acc[r]);
          }
        }
        int col = ct2*16 + lane15;
        float bias = bdec[col];
        #pragma unroll
        for (int r=0;r<4;r++){
          #pragma unroll
          for (int q=0;q<4;q++){
            int bb = r*16 + quad*4 + q;
            ws->att2[bb*AAT + col] = acc[r][q] + bias;
          }
        }
      }
    }
    grid.sync();
    // ---- phase C ----
    sh_a2[tid]     = ws->att2[b*AAT + tid];
    sh_a2[tid+256] = ws->att2[b*AAT + tid + 256];
    __syncthreads();
    for (int n = wid; n < NN; n += 4){
      const float* at1 = ws->att1 + (size_t)(b*NN + n)*AAT + lane*8;
      const float* a2p = sh_a2 + lane*8;
      const float* wfp = sh_wf + lane*8;
      float s = 0.f;
      #pragma unroll
      for (int j=0;j<8;j++){
        float v = at1[j] + a2p[j];
        v = fmaxf(v, 0.0f);
        s += v * wfp[j];
      }
      #pragma unroll
      for (int off=32; off; off>>=1) s += __shfl_xor(s, off, 64);
      if (lane==0) sh_e[n] = s;
    }
    __syncthreads();
    if (wid == 0){
      float e = (lane < NN) ? sh_e[lane] : -1e30f;
      float m = e;
      #pragma unroll
      for (int off=32; off; off>>=1) m = fmaxf(m, __shfl_xor(m, off, 64));
      float p = (lane < NN) ? expf(e - m) : 0.0f;
      float su = p;
      #pragma unroll
      for (int off=32; off; off>>=1) su += __shfl_xor(su, off, 64);
      float al = p / su;
      if (lane < NN){
        sal[lane] = al;
        if (jhalf == 0) out[ALPHA_OFF + (size_t)(b*NSTEP + t)*NN + lane] = al;
      }
    }
    __syncthreads();
    // gates + LSTM pointwise
    size_t eoff = ((size_t)(t*64 + b))*(4*HH) + jj;
    size_t hoff = (size_t)b*(4*HH) + jj;
    float gi = ws->embg[eoff]        + ws->hwhh[hoff];
    float gf = ws->embg[eoff+512]    + ws->hwhh[hoff+512];
    float gg = ws->embg[eoff+1024]   + ws->hwhh[hoff+1024];
    float go = ws->embg[eoff+1536]   + ws->hwhh[hoff+1536];
    const float* fgp = ws->u.fg + (size_t)b*NN*(4*HH) + jj;
    #pragma unroll 7
    for (int n=0;n<NN;n++){
      float a = sal[n];
      gi += a*fgp[0];
      gf += a*fgp[512];
      gg += a*fgp[1024];
      go += a*fgp[1536];
      fgp += 4*HH;
    }
    float co = ws->c[par][b*HH + jj];
    float cn = sigm(gf)*co + sigm(gi)*tanhf(gg);
    float hn = sigm(go)*tanhf(cn);
    ws->c[p2][b*HH + jj] = cn;
    bf16 hi_ = (bf16)hn;
    bf16 lo_ = (bf16)(hn - (float)hi_);
    int kc = jj>>5, lane_w = ((jj&31)>>3)*16 + (b&15), j8 = jj&7;
    int offh = (((b>>4)*16 + kc)*64 + lane_w)*8 + j8;
    ws->h_hi[p2][offh] = hi_;
    ws->h_lo[p2][offh] = lo_;
    size_t offhist = ((((size_t)t*4 + (b>>4))*16 + kc)*64 + lane_w)*8 + j8;
    ws->hist_hi[offhist] = hi_;
    ws->hist_lo[offhist] = lo_;
    grid.sync();
  }
}

// ---------------- final pred GEMM: [1600 x 10000] = hist @ Wfcn^T (T16) ------------
__global__ __launch_bounds__(256) void k_pred(Wks* __restrict__ ws,
    const float* __restrict__ bfcn, float* __restrict__ out)
{
  int wid = threadIdx.x>>6, lane = threadIdx.x&63;
  int mt = blockIdx.y*4 + wid;
  int nt = blockIdx.x;
  if (mt >= NSTEP) return;
  int lane15 = lane&15, quad = lane>>4;
  int n0 = nt*64;
  f32x4 acc[4][4] = {};
  for (int kc=0; kc<16; kc++){
    bf16x8 a_hi[4], a_lo[4], bw[4];
    #pragma unroll
    for (int i=0;i<4;i++){
      a_hi[i] = ldb8(ws->hist_hi + (((size_t)(mt*4+i)*16 + kc)*64 + lane)*8);
      a_lo[i] = ldb8(ws->hist_lo + (((size_t)(mt*4+i)*16 + kc)*64 + lane)*8);
    }
    #pragma unroll
    for (int u=0;u<4;u++)
      bw[u] = ldb8(ws->u.w.Wfcn_hi + (((size_t)(nt*4+u)*16 + kc)*64 + lane)*8);
    #pragma unroll
    for (int u=0;u<4;u++){
      #pragma unroll
      for (int i=0;i<4;i++){
        acc[u][i] = mfma16(a_hi[i], bw[u], acc[u][i]);
        acc[u][i] = mfma16(a_lo[i], bw[u], acc[u][i]);
      }
    }
  }
  #pragma unroll
  for (int u=0;u<4;u++){
    int vc = n0 + u*16 + lane15;
    if (vc < VV){
      float bias = bfcn[vc];
      #pragma unroll
      for (int i=0;i<4;i++){
        #pragma unroll
        for (int r=0;r<4;r++){
          int row = mt*64 + i*16 + quad*4 + r;   // row = s*64 + b
          int sstep = row >> 6, bidx = row & 63;
          out[(size_t)(bidx*NSTEP + sstep)*VV + vc] = acc[u][i][r] + bias;
        }
      }
    }
  }
}

extern "C" void kernel_launch(void* const* d_in, const int* in_sizes, int n_in,
                              void* d_out, int out_size, void* d_ws, size_t ws_size,
                              hipStream_t stream)
{
  const float* feat = (const float*)d_in[0];
  const int*   caps = (const int*)d_in[1];
  const float* emb  = (const float*)d_in[2];
  const float* Wih  = (const float*)d_in[3];
  const float* bih  = (const float*)d_in[4];
  const float* Whh  = (const float*)d_in[5];
  const float* bhh  = (const float*)d_in[6];
  const float* Wenc = (const float*)d_in[7];
  const float* benc = (const float*)d_in[8];
  const float* Wdec = (const float*)d_in[9];
  const float* bdec = (const float*)d_in[10];
  const float* Wfull= (const float*)d_in[11];
  const float* bfull= (const float*)d_in[12];
  const float* Winh = (const float*)d_in[13];
  const float* binh = (const float*)d_in[14];
  const float* Winc = (const float*)d_in[15];
  const float* binc = (const float*)d_in[16];
  const float* Wfcn = (const float*)d_in[17];
  const float* bfcn = (const float*)d_in[18];
  float* out = (float*)d_out;
  Wks* ws = (Wks*)d_ws;
  if (ws_size < sizeof(Wks)) return;
  (void)bfull;

  #define SW(src, hi, lo, R, K) do { int nt_ = ((R+15)/16)*((K)/32); \
    hipLaunchKernelGGL(k_cvt_sw, dim3((nt_*64+255)/256), dim3(256), 0, stream, \
        src, hi, lo, R, K, nt_); } while(0)
  SW(Wih,  ws->Wih_hi,  ws->Wih_lo,  2048, 2560);
  SW(Whh,  ws->Whh_hi,  ws->Whh_lo,  2048, 512);
  SW(Wenc, ws->Wenc_hi, (bf16*)nullptr, 512, 2048);
  SW(Wdec, ws->Wdec_hi, (bf16*)nullptr, 512, 512);
  SW(Winh, ws->u.w.Winh_hi, (bf16*)nullptr, 512, 2048);
  SW(Winc, ws->u.w.Winc_hi, (bf16*)nullptr, 512, 2048);
  hipLaunchKernelGGL(k_emb, dim3(400), dim3(256), 0, stream, caps, emb, ws);
  hipLaunchKernelGGL(k_mean, dim3(512), dim3(256), 0, stream, feat, ws);
  hipLaunchKernelGGL(k_init, dim3(16), dim3(256), 0, stream, ws, binh, binc);
  hipLaunchKernelGGL(k_embg, dim3(800), dim3(256), 0, stream, ws, bih, bhh);
  hipLaunchKernelGGL(k_enc, dim3(980), dim3(256), 0, stream, feat, benc, ws);
  {
    void* kargs[4];
    kargs[0] = (void*)&ws;
    kargs[1] = (void*)&bdec;
    kargs[2] = (void*)&Wfull;
    kargs[3] = (void*)&out;
    hipLaunchCooperativeKernel((const void*)k_loop, dim3(128), dim3(256),
                               kargs, 0, stream);
  }
  // fg dead now: reuse its space for the Wfcn swizzle, then pred
  SW(Wfcn, ws->u.w.Wfcn_hi, (bf16*)nullptr, 10000, 512);
  #undef SW
  hipLaunchKernelGGL(k_pred, dim3(157, 7), dim3(256), 0, stream, ws, bfcn, out);
}